// Round 2
// baseline (10874.782 us; speedup 1.0000x reference)
//
#include <hip/hip_runtime.h>
#include <hip/hip_bf16.h>
#include <math.h>

#define N_TOK   4096
#define D_MODEL 1024
#define VOCAB   32000
#define NH      16
#define DHEAD   64
#define DEPTH   4
#define PREFIX  3072
#define M_TOK   1024      /* N_TOK - PREFIX */
#define FF_DIM  4096
#define INNER   1024

typedef __hip_bfloat16 bf16;

__device__ __forceinline__ float ldf(const float* p, size_t i) { return p[i]; }
__device__ __forceinline__ float ldf(const bf16*  p, size_t i) { return __bfloat162float(p[i]); }

// ---------------- embedding for the residual stream rows only ----------------
// h[r,c] = tok_emb[x[PREFIX+r]][c] + pos_emb[PREFIX+r][c]   (r in [0,1024))
__global__ __launch_bounds__(256)
void embed_h_kernel(const int* __restrict__ x,
                    const float* __restrict__ tok,
                    const float* __restrict__ pos,
                    float* __restrict__ h)
{
    int idx = blockIdx.x * 256 + threadIdx.x;   // over M_TOK*D_MODEL
    int r = idx >> 10;
    int c = idx & 1023;
    int row = PREFIX + r;
    h[idx] = tok[(size_t)x[row] * D_MODEL + c] + pos[(size_t)row * D_MODEL + c];
}

// ---------------- layernorm: one block per row ----------------
__global__ __launch_bounds__(256)
void ln_kernel(const float* __restrict__ src,
               const float* __restrict__ g,
               const float* __restrict__ b,
               float* __restrict__ dst)
{
    __shared__ float r1[256], r2[256];
    int row = blockIdx.x, tid = threadIdx.x;
    const float* xr = src + (size_t)row * D_MODEL;
    float s = 0.f, s2 = 0.f;
    for (int d = tid; d < D_MODEL; d += 256) { float v = xr[d]; s += v; s2 += v * v; }
    r1[tid] = s; r2[tid] = s2; __syncthreads();
    for (int st = 128; st > 0; st >>= 1) {
        if (tid < st) { r1[tid] += r1[tid + st]; r2[tid] += r2[tid + st]; }
        __syncthreads();
    }
    float mean = r1[0] * (1.f / D_MODEL);
    float var  = r2[0] * (1.f / D_MODEL) - mean * mean;
    float rstd = rsqrtf(var + 1e-5f);
    for (int d = tid; d < D_MODEL; d += 256)
        dst[(size_t)row * D_MODEL + d] = (xr[d] - mean) * rstd * g[d] + b[d];
}

// ---------------- generic tiled GEMM: C[M,Nc] = A[M,K] @ W[K,Nc](f32) ----------------
// A is f32 or bf16 (template), or implicit embedding (gtok != null):
//   A[row][k] = tok[x[row]*1024 + k] + pos[row*1024 + k]
// epilogue: optional exact gelu, optional f32 bias, optional f32 residual,
// output to f32 (Cf) or bf16 (Cb).
#define BM 64
#define BN 64
#define BK 16
template<typename TA>
__global__ __launch_bounds__(256)
void gemm_kernel(const TA* __restrict__ A, int lda, int K,
                 const float* __restrict__ W, int ldw,
                 const float* __restrict__ bias,
                 const float* __restrict__ resid, int ldr,
                 float* __restrict__ Cf, bf16* __restrict__ Cb, int ldc,
                 int do_gelu,
                 const int* __restrict__ gx,
                 const float* __restrict__ gtok,
                 const float* __restrict__ gpos)
{
    __shared__ float As[BM][BK + 1];
    __shared__ float Bs[BK][BN];
    int tid = threadIdx.x;
    int tx = tid & 15, ty = tid >> 4;
    int n0 = blockIdx.x * BN, m0 = blockIdx.y * BM;
    float acc[4][4] = {};
    for (int k0 = 0; k0 < K; k0 += BK) {
#pragma unroll
        for (int l = 0; l < 4; l++) {          // A tile: 64x16
            int e  = tid + l * 256;
            int mm = e >> 4, kk = e & 15;
            int row = m0 + mm;
            float av;
            if (gtok)
                av = gtok[(size_t)gx[row] * D_MODEL + k0 + kk]
                   + gpos[(size_t)row * D_MODEL + k0 + kk];
            else
                av = ldf(A, (size_t)row * lda + k0 + kk);
            As[mm][kk] = av;
        }
#pragma unroll
        for (int l = 0; l < 4; l++) {          // W tile: 16x64, coalesced along n
            int e  = tid + l * 256;
            int kk = e >> 6, nn = e & 63;
            Bs[kk][nn] = W[(size_t)(k0 + kk) * ldw + n0 + nn];
        }
        __syncthreads();
#pragma unroll
        for (int kk = 0; kk < BK; kk++) {
            float a[4], b[4];
#pragma unroll
            for (int i = 0; i < 4; i++) a[i] = As[ty + 16 * i][kk];
#pragma unroll
            for (int j = 0; j < 4; j++) b[j] = Bs[kk][tx + 16 * j];
#pragma unroll
            for (int i = 0; i < 4; i++)
#pragma unroll
                for (int j = 0; j < 4; j++)
                    acc[i][j] += a[i] * b[j];
        }
        __syncthreads();
    }
#pragma unroll
    for (int i = 0; i < 4; i++) {
        int m = m0 + ty + 16 * i;
#pragma unroll
        for (int j = 0; j < 4; j++) {
            int n = n0 + tx + 16 * j;
            float v = acc[i][j];
            if (do_gelu) v = 0.5f * v * (1.f + erff(v * 0.70710678118f));
            if (bias)    v += bias[n];
            if (resid)   v += resid[(size_t)m * ldr + n];
            if (Cf) Cf[(size_t)m * ldc + n] = v;
            else    Cb[(size_t)m * ldc + n] = __float2bfloat16(v);
        }
    }
}

// ---------------- attention: one block per (query row i, head hh) ----------------
// q,k,v stored bf16; attends keys j in [0, i + delta + 1); scores in LDS (<=4096)
__global__ __launch_bounds__(256)
void attn_kernel(const bf16* __restrict__ q, int ldq,
                 const bf16* __restrict__ k, int ldk,
                 const bf16* __restrict__ v, int ldv,
                 float* __restrict__ out,
                 int delta)
{
    __shared__ float sc[4096];
    __shared__ float qs[DHEAD];
    __shared__ float rbuf[256];
    __shared__ float part[4][DHEAD];
    int tid = threadIdx.x;
    int i  = blockIdx.x >> 4;      // / NH
    int hh = blockIdx.x & 15;
    int jmax = i + delta + 1;
    if (tid < DHEAD)
        qs[tid] = __bfloat162float(q[(size_t)i * ldq + hh * DHEAD + tid]) * 0.125f; // DH^-0.5
    __syncthreads();

    // pass 1: scores + local max
    float lmax = -1e30f;
    for (int j = tid; j < jmax; j += 256) {
        const bf16* kr = k + (size_t)j * ldk + hh * DHEAD;
        float s = 0.f;
#pragma unroll
        for (int d = 0; d < DHEAD; d++) s += qs[d] * __bfloat162float(kr[d]);
        sc[j] = s;
        lmax = fmaxf(lmax, s);
    }
    rbuf[tid] = lmax; __syncthreads();
    for (int st = 128; st > 0; st >>= 1) {
        if (tid < st) rbuf[tid] = fmaxf(rbuf[tid], rbuf[tid + st]);
        __syncthreads();
    }
    float gmax = rbuf[0];
    __syncthreads();

    // pass 2: exp + sum
    float lsum = 0.f;
    for (int j = tid; j < jmax; j += 256) {
        float p = expf(sc[j] - gmax);
        sc[j] = p; lsum += p;
    }
    rbuf[tid] = lsum; __syncthreads();
    for (int st = 128; st > 0; st >>= 1) {
        if (tid < st) rbuf[tid] += rbuf[tid + st];
        __syncthreads();
    }
    float inv = 1.f / rbuf[0];
    __syncthreads();

    // pass 3: out[d] = sum_j p_j * v[j][d], 4 j-groups x 64 dims
    int d = tid & 63, g = tid >> 6;
    float acc = 0.f;
    for (int j = g; j < jmax; j += 4)
        acc += sc[j] * __bfloat162float(v[(size_t)j * ldv + hh * DHEAD + d]);
    part[g][d] = acc;
    __syncthreads();
    if (tid < DHEAD) {
        float o = (part[0][tid] + part[1][tid] + part[2][tid] + part[3][tid]) * inv;
        out[(size_t)i * INNER + hh * DHEAD + tid] = o;
    }
}

extern "C" void kernel_launch(void* const* d_in, const int* in_sizes, int n_in,
                              void* d_out, int out_size, void* d_ws, size_t ws_size,
                              hipStream_t stream)
{
    const int*   x        = (const int*)  d_in[0];
    const float* tok_emb  = (const float*)d_in[1];
    const float* pos_emb  = (const float*)d_in[2];
    const float* ca_ln_g  = (const float*)d_in[3];
    const float* ca_ln_b  = (const float*)d_in[4];
    const float* ca_wq    = (const float*)d_in[5];
    const float* ca_wkv   = (const float*)d_in[6];
    const float* ca_wo    = (const float*)d_in[7];
    const float* ca_bo    = (const float*)d_in[8];
    const float* cf_ln_g  = (const float*)d_in[9];
    const float* cf_ln_b  = (const float*)d_in[10];
    const float* cf_w1    = (const float*)d_in[11];
    const float* cf_w2    = (const float*)d_in[12];
    const float* la_ln_g  = (const float*)d_in[13];
    const float* la_ln_b  = (const float*)d_in[14];
    const float* la_wqkv  = (const float*)d_in[15];
    const float* la_wo    = (const float*)d_in[16];
    const float* lf_ln_g  = (const float*)d_in[17];
    const float* lf_ln_b  = (const float*)d_in[18];
    const float* lf_w1    = (const float*)d_in[19];
    const float* lf_w2    = (const float*)d_in[20];
    const float* w_logits = (const float*)d_in[21];
    float* out = (float*)d_out;

    // compact workspace: 3M persistent f32 + 4.5M-f32-sized arena = 30 MB total
    float* h     = (float*)d_ws;            // 1024x1024 f32 (residual stream)
    float* xn    = h  + (1u << 20);         // 1024x1024 f32
    float* ao    = xn + (1u << 20);         // 1024x1024 f32
    float* arena = ao + (1u << 20);         // reused per phase
    bf16*  qb    = (bf16*)arena;                       // cross: 1024x1024 bf16
    bf16*  kvb   = qb + (size_t)M_TOK * INNER;         // cross: 4096x2048 bf16
    bf16*  qkvb  = (bf16*)arena;                       // self:  1024x3072 bf16
    float* ff    = arena;                              // ffwd:  1024x4096 f32

    dim3 b256(256);

    auto gemmF = [&](const float* A, int lda, int K, const float* W, int ldw,
                     const float* bias, const float* resid, int ldr,
                     float* Cf, bf16* Cb, int ldc, int Mrows, int Ncols, int gelu,
                     const int* gx, const float* gtok, const float* gpos) {
        dim3 grid(Ncols / BN, Mrows / BM);
        gemm_kernel<float><<<grid, b256, 0, stream>>>(A, lda, K, W, ldw, bias, resid, ldr,
                                                      Cf, Cb, ldc, gelu, gx, gtok, gpos);
    };
    auto gemmH = [&](const bf16* A, int lda, int K, const float* W, int ldw,
                     const float* resid, int ldr,
                     float* Cf, int ldc, int Mrows, int Ncols) {
        dim3 grid(Ncols / BN, Mrows / BM);
        gemm_kernel<bf16><<<grid, b256, 0, stream>>>(A, lda, K, W, ldw, nullptr, resid, ldr,
                                                     Cf, nullptr, ldc, 0,
                                                     nullptr, nullptr, nullptr);
    };

    // residual stream h = embedding rows PREFIX..N-1
    embed_h_kernel<<<(M_TOK * D_MODEL) / 256, b256, 0, stream>>>(x, tok_emb, pos_emb, h);

    // ---- cross-attention block ----
    ln_kernel<<<M_TOK, b256, 0, stream>>>(h, ca_ln_g, ca_ln_b, xn);
    gemmF(xn, D_MODEL, D_MODEL, ca_wq, INNER, nullptr, nullptr, 0,
          nullptr, qb, INNER, M_TOK, INNER, 0, nullptr, nullptr, nullptr);
    // kv_ctx: A = embedding rows 0..PREFIX-1 computed on the fly
    gemmF(nullptr, 0, D_MODEL, ca_wkv, 2 * INNER, nullptr, nullptr, 0,
          nullptr, kvb, 2 * INNER, PREFIX, 2 * INNER, 0, x, tok_emb, pos_emb);
    // kv_in: A = xn
    gemmF(xn, D_MODEL, D_MODEL, ca_wkv, 2 * INNER, nullptr, nullptr, 0,
          nullptr, kvb + (size_t)PREFIX * 2 * INNER, 2 * INNER, M_TOK, 2 * INNER, 0,
          nullptr, nullptr, nullptr);
    attn_kernel<<<M_TOK * NH, b256, 0, stream>>>(qb, INNER, kvb, 2 * INNER,
                                                 kvb + INNER, 2 * INNER, ao, PREFIX);
    gemmF(ao, INNER, INNER, ca_wo, D_MODEL, ca_bo, h, D_MODEL,
          h, nullptr, D_MODEL, M_TOK, D_MODEL, 0, nullptr, nullptr, nullptr);

    // ---- cross ffwd ----
    ln_kernel<<<M_TOK, b256, 0, stream>>>(h, cf_ln_g, cf_ln_b, xn);
    gemmF(xn, D_MODEL, D_MODEL, cf_w1, FF_DIM, nullptr, nullptr, 0,
          ff, nullptr, FF_DIM, M_TOK, FF_DIM, 1, nullptr, nullptr, nullptr);
    gemmF(ff, FF_DIM, FF_DIM, cf_w2, D_MODEL, nullptr, h, D_MODEL,
          h, nullptr, D_MODEL, M_TOK, D_MODEL, 0, nullptr, nullptr, nullptr);

    // ---- 4 self-attention transformer blocks ----
    for (int l = 0; l < DEPTH; l++) {
        ln_kernel<<<M_TOK, b256, 0, stream>>>(h, la_ln_g + l * D_MODEL,
                                              la_ln_b + l * D_MODEL, xn);
        gemmF(xn, D_MODEL, D_MODEL, la_wqkv + (size_t)l * D_MODEL * 3 * INNER, 3 * INNER,
              nullptr, nullptr, 0, nullptr, qkvb, 3 * INNER, M_TOK, 3 * INNER, 0,
              nullptr, nullptr, nullptr);
        attn_kernel<<<M_TOK * NH, b256, 0, stream>>>(qkvb, 3 * INNER,
                                                     qkvb + INNER, 3 * INNER,
                                                     qkvb + 2 * INNER, 3 * INNER, ao, 0);
        gemmF(ao, INNER, INNER, la_wo + (size_t)l * INNER * D_MODEL, D_MODEL,
              nullptr, h, D_MODEL, h, nullptr, D_MODEL, M_TOK, D_MODEL, 0,
              nullptr, nullptr, nullptr);
        ln_kernel<<<M_TOK, b256, 0, stream>>>(h, lf_ln_g + l * D_MODEL,
                                              lf_ln_b + l * D_MODEL, xn);
        gemmF(xn, D_MODEL, D_MODEL, lf_w1 + (size_t)l * D_MODEL * FF_DIM, FF_DIM,
              nullptr, nullptr, 0, ff, nullptr, FF_DIM, M_TOK, FF_DIM, 1,
              nullptr, nullptr, nullptr);
        gemmF(ff, FF_DIM, FF_DIM, lf_w2 + (size_t)l * FF_DIM * D_MODEL, D_MODEL,
              nullptr, h, D_MODEL, h, nullptr, D_MODEL, M_TOK, D_MODEL, 0,
              nullptr, nullptr, nullptr);
    }

    // ---- logits head: out = h @ w_logits (f32 out) ----
    gemmF(h, D_MODEL, D_MODEL, w_logits, VOCAB, nullptr, nullptr, 0,
          out, nullptr, VOCAB, M_TOK, VOCAB, 0, nullptr, nullptr, nullptr);
}

// Round 3
// 4866.618 us; speedup vs baseline: 2.2346x; 2.2346x over previous
//
#include <hip/hip_runtime.h>
#include <hip/hip_bf16.h>
#include <math.h>

#define N_TOK   4096
#define D_MODEL 1024
#define VOCAB   32000
#define NH      16
#define DHEAD   64
#define DEPTH   4
#define PREFIX  3072
#define M_TOK   1024      /* N_TOK - PREFIX */
#define FF_DIM  4096
#define INNER   1024

typedef __hip_bfloat16 bf16;
typedef __attribute__((ext_vector_type(8))) short bf16x8;  // 8 bf16 = 4 VGPRs (MFMA A/B frag)
typedef __attribute__((ext_vector_type(4))) float f32x4;   // MFMA C/D frag

__device__ __forceinline__ unsigned short bfbits(float f) {
    union { float f; unsigned u; } x; x.f = f;
    return (unsigned short)((x.u + 0x7fffu + ((x.u >> 16) & 1u)) >> 16);  // RNE
}
__device__ __forceinline__ float2 bf2(unsigned u) {
    union { unsigned x; float f; } lo, hi;
    lo.x = u << 16; hi.x = u & 0xffff0000u;
    return make_float2(lo.f, hi.f);
}

// ---------------- residual-stream embedding (rows PREFIX..N-1), f32 ----------------
__global__ __launch_bounds__(256)
void embed_h_kernel(const int* __restrict__ x,
                    const float* __restrict__ tok,
                    const float* __restrict__ pos,
                    float* __restrict__ h)
{
    int idx = blockIdx.x * 256 + threadIdx.x;   // over M_TOK*D_MODEL
    int r = idx >> 10, c = idx & 1023;
    int row = PREFIX + r;
    h[idx] = tok[(size_t)x[row] * D_MODEL + c] + pos[(size_t)row * D_MODEL + c];
}

// ---------------- prefix embedding (rows 0..PREFIX-1), bf16 ----------------
__global__ __launch_bounds__(256)
void embed_p_kernel(const int* __restrict__ x,
                    const float* __restrict__ tok,
                    const float* __restrict__ pos,
                    bf16* __restrict__ eb)
{
    int idx = blockIdx.x * 256 + threadIdx.x;   // over PREFIX*D_MODEL
    int r = idx >> 10, c = idx & 1023;
    eb[idx] = __float2bfloat16(tok[(size_t)x[r] * D_MODEL + c] + pos[(size_t)r * D_MODEL + c]);
}

// ---------------- layernorm: f32 in, bf16 out ----------------
__global__ __launch_bounds__(256)
void ln_kernel(const float* __restrict__ src,
               const float* __restrict__ g,
               const float* __restrict__ b,
               bf16* __restrict__ dst)
{
    __shared__ float r1[256], r2[256];
    int row = blockIdx.x, tid = threadIdx.x;
    const float* xr = src + (size_t)row * D_MODEL;
    float s = 0.f, s2 = 0.f;
    for (int d = tid; d < D_MODEL; d += 256) { float v = xr[d]; s += v; s2 += v * v; }
    r1[tid] = s; r2[tid] = s2; __syncthreads();
    for (int st = 128; st > 0; st >>= 1) {
        if (tid < st) { r1[tid] += r1[tid + st]; r2[tid] += r2[tid + st]; }
        __syncthreads();
    }
    float mean = r1[0] * (1.f / D_MODEL);
    float var  = r2[0] * (1.f / D_MODEL) - mean * mean;
    float rstd = rsqrtf(var + 1e-5f);
    for (int d = tid; d < D_MODEL; d += 256)
        dst[(size_t)row * D_MODEL + d] =
            __float2bfloat16((xr[d] - mean) * rstd * g[d] + b[d]);
}

// ---------------- MFMA bf16 GEMM: C[M,N] = A[M,K](bf16) @ W[K,N](f32) ----------------
// 128x128x32 tiles, 4 waves, each wave 64x64 via 4x4 fragments of 16x16x32.
// W staged f32 -> bf16, transposed into Bt[n][k] so b-frags are ds_read_b128.
// Epilogue: optional exact gelu, f32 bias, f32 residual; writes Cf (f32) and/or Cb (bf16).
#define BM 128
#define BN 128
#define BK 32
#define ASTR 40   /* LDS row stride (elems): 32 + 8 pad, keeps 16B alignment */
__global__ __launch_bounds__(256)
void gemm_kernel(const bf16* __restrict__ A, int lda, int K,
                 const float* __restrict__ W, int ldw,
                 const float* __restrict__ bias,
                 const float* __restrict__ resid, int ldr,
                 float* __restrict__ Cf, bf16* __restrict__ Cb, int ldc,
                 int do_gelu)
{
    __shared__ bf16 As[BM * ASTR];
    __shared__ bf16 Bs[BN * ASTR];   // transposed: Bs[n][k]
    const int tid = threadIdx.x;
    const int m0 = blockIdx.y * BM, n0 = blockIdx.x * BN;
    // A staging: thread -> (row, 16-elem half)
    const int ar = tid >> 1;
    const int ac = (tid & 1) << 4;
    // B staging: thread -> (k pair, 8-col group)
    const int bk2 = (tid >> 4) << 1;      // 0,2,..,30
    const int bn8 = (tid & 15) << 3;      // 0,8,..,120
    // compute mapping
    const int lane = tid & 63;
    const int wv   = tid >> 6;
    const int wm = (wv >> 1) * 64, wn = (wv & 1) * 64;
    const int l16 = lane & 15, quad = lane >> 4;

    f32x4 acc[4][4];
#pragma unroll
    for (int i = 0; i < 4; i++)
#pragma unroll
        for (int j = 0; j < 4; j++)
#pragma unroll
            for (int r = 0; r < 4; r++) acc[i][j][r] = 0.f;

    const unsigned short* Ag = (const unsigned short*)A + (size_t)(m0 + ar) * lda + ac;
    const float*          Wg = W + (size_t)bk2 * ldw + n0 + bn8;

    for (int k0 = 0; k0 < K; k0 += BK) {
        uint4 av0 = *(const uint4*)(Ag + k0);
        uint4 av1 = *(const uint4*)(Ag + k0 + 8);
        const float* wp = Wg + (size_t)k0 * ldw;
        float4 f0 = *(const float4*)(wp);
        float4 f1 = *(const float4*)(wp + 4);
        float4 f2 = *(const float4*)(wp + ldw);
        float4 f3 = *(const float4*)(wp + ldw + 4);
        *(uint4*)&As[ar * ASTR + ac]     = av0;
        *(uint4*)&As[ar * ASTR + ac + 8] = av1;
        float lo[8] = {f0.x, f0.y, f0.z, f0.w, f1.x, f1.y, f1.z, f1.w};
        float hi[8] = {f2.x, f2.y, f2.z, f2.w, f3.x, f3.y, f3.z, f3.w};
#pragma unroll
        for (int q = 0; q < 8; q++) {
            unsigned p = (unsigned)bfbits(lo[q]) | ((unsigned)bfbits(hi[q]) << 16);
            *(unsigned*)((unsigned short*)Bs + (size_t)(bn8 + q) * ASTR + bk2) = p;
        }
        __syncthreads();
        bf16x8 af[4], bfr[4];
#pragma unroll
        for (int i = 0; i < 4; i++)
            af[i] = *(const bf16x8*)&As[(wm + i * 16 + l16) * ASTR + quad * 8];
#pragma unroll
        for (int j = 0; j < 4; j++)
            bfr[j] = *(const bf16x8*)&Bs[(wn + j * 16 + l16) * ASTR + quad * 8];
#pragma unroll
        for (int i = 0; i < 4; i++)
#pragma unroll
            for (int j = 0; j < 4; j++)
                acc[i][j] = __builtin_amdgcn_mfma_f32_16x16x32_bf16(af[i], bfr[j],
                                                                    acc[i][j], 0, 0, 0);
        __syncthreads();
    }
#pragma unroll
    for (int i = 0; i < 4; i++) {
#pragma unroll
        for (int r = 0; r < 4; r++) {
            int mg = m0 + wm + i * 16 + quad * 4 + r;
#pragma unroll
            for (int j = 0; j < 4; j++) {
                int ng = n0 + wn + j * 16 + l16;
                float v = acc[i][j][r];
                if (do_gelu) v = 0.5f * v * (1.f + erff(v * 0.70710678118f));
                if (bias)    v += bias[ng];
                if (resid)   v += resid[(size_t)mg * ldr + ng];
                if (Cf) Cf[(size_t)mg * ldc + ng] = v;
                if (Cb) Cb[(size_t)mg * ldc + ng] = __float2bfloat16(v);
            }
        }
    }
}

// ---------------- attention: one block per (query row i, head hh), vectorized ----------------
__global__ __launch_bounds__(256)
void attn_kernel(const bf16* __restrict__ q, int ldq,
                 const bf16* __restrict__ k, int ldk,
                 const bf16* __restrict__ v, int ldv,
                 bf16* __restrict__ out, int ldo,
                 int delta)
{
    __shared__ float sc[4096];
    __shared__ float qs[DHEAD];
    __shared__ float red[256];
    __shared__ float part[16][64];
    int tid = threadIdx.x;
    int i  = blockIdx.x >> 4;
    int hh = blockIdx.x & 15;
    int jmax = i + delta + 1;
    if (tid < DHEAD)
        qs[tid] = __bfloat162float(q[(size_t)i * ldq + hh * DHEAD + tid]) * 0.125f;
    __syncthreads();

    // pass 1: scores (uint4 = 8 bf16 per load) + local max
    float lmax = -1e30f;
    for (int j = tid; j < jmax; j += 256) {
        const uint4* kr = (const uint4*)((const unsigned short*)k + (size_t)j * ldk + hh * DHEAD);
        float s = 0.f;
#pragma unroll
        for (int d8 = 0; d8 < 8; d8++) {
            uint4 raw = kr[d8];
            float2 p0 = bf2(raw.x), p1 = bf2(raw.y), p2 = bf2(raw.z), p3 = bf2(raw.w);
            const float* qd = &qs[d8 * 8];
            s += qd[0] * p0.x + qd[1] * p0.y + qd[2] * p1.x + qd[3] * p1.y
               + qd[4] * p2.x + qd[5] * p2.y + qd[6] * p3.x + qd[7] * p3.y;
        }
        sc[j] = s;
        lmax = fmaxf(lmax, s);
    }
    red[tid] = lmax; __syncthreads();
    for (int st = 128; st > 0; st >>= 1) {
        if (tid < st) red[tid] = fmaxf(red[tid], red[tid + st]);
        __syncthreads();
    }
    float gmax = red[0];
    __syncthreads();

    // pass 2: exp + sum
    float lsum = 0.f;
    for (int j = tid; j < jmax; j += 256) {
        float p = __expf(sc[j] - gmax);
        sc[j] = p; lsum += p;
    }
    red[tid] = lsum; __syncthreads();
    for (int st = 128; st > 0; st >>= 1) {
        if (tid < st) red[tid] += red[tid + st];
        __syncthreads();
    }
    float inv = 1.f / red[0];
    __syncthreads();

    // pass 3: O[d] = sum_j p_j V[j][d]; 16 j-groups x 16 d-quads
    int dg = tid & 15, g = tid >> 4;
    float a0 = 0.f, a1 = 0.f, a2 = 0.f, a3 = 0.f;
    for (int j = g; j < jmax; j += 16) {
        const uint2* vr = (const uint2*)((const unsigned short*)v + (size_t)j * ldv
                                         + hh * DHEAD + dg * 4);
        uint2 raw = *vr;
        float2 x0 = bf2(raw.x), x1 = bf2(raw.y);
        float p = sc[j];
        a0 += p * x0.x; a1 += p * x0.y; a2 += p * x1.x; a3 += p * x1.y;
    }
    *(float4*)&part[g][dg * 4] = make_float4(a0, a1, a2, a3);
    __syncthreads();
    if (tid < DHEAD) {
        float o = 0.f;
#pragma unroll
        for (int g2 = 0; g2 < 16; g2++) o += part[g2][tid];
        out[(size_t)i * ldo + hh * DHEAD + tid] = __float2bfloat16(o * inv);
    }
}

extern "C" void kernel_launch(void* const* d_in, const int* in_sizes, int n_in,
                              void* d_out, int out_size, void* d_ws, size_t ws_size,
                              hipStream_t stream)
{
    const int*   x        = (const int*)  d_in[0];
    const float* tok_emb  = (const float*)d_in[1];
    const float* pos_emb  = (const float*)d_in[2];
    const float* ca_ln_g  = (const float*)d_in[3];
    const float* ca_ln_b  = (const float*)d_in[4];
    const float* ca_wq    = (const float*)d_in[5];
    const float* ca_wkv   = (const float*)d_in[6];
    const float* ca_wo    = (const float*)d_in[7];
    const float* ca_bo    = (const float*)d_in[8];
    const float* cf_ln_g  = (const float*)d_in[9];
    const float* cf_ln_b  = (const float*)d_in[10];
    const float* cf_w1    = (const float*)d_in[11];
    const float* cf_w2    = (const float*)d_in[12];
    const float* la_ln_g  = (const float*)d_in[13];
    const float* la_ln_b  = (const float*)d_in[14];
    const float* la_wqkv  = (const float*)d_in[15];
    const float* la_wo    = (const float*)d_in[16];
    const float* lf_ln_g  = (const float*)d_in[17];
    const float* lf_ln_b  = (const float*)d_in[18];
    const float* lf_w1    = (const float*)d_in[19];
    const float* lf_w2    = (const float*)d_in[20];
    const float* w_logits = (const float*)d_in[21];
    float* out = (float*)d_out;

    // workspace: 34 MB
    float* h     = (float*)d_ws;                       // 1024x1024 f32
    bf16*  hb    = (bf16*)(h + (1 << 20));             // 1024x1024 bf16
    bf16*  xnb   = hb  + (1 << 20);                    // 1024x1024 bf16
    bf16*  aob   = xnb + (1 << 20);                    // 1024x1024 bf16
    bf16*  arena = aob + (1 << 20);
    bf16*  qb    = arena;                              // cross: 1024x1024
    bf16*  kvb   = arena + (1 << 20);                  // cross: 4096x2048
    bf16*  eb    = kvb + (size_t)N_TOK * 2 * INNER;    // cross: 3072x1024
    bf16*  ffb   = arena;                              // ffwd:  1024x4096
    bf16*  qkvb  = arena;                              // self:  1024x3072

    dim3 b256(256);
    auto gemm = [&](const bf16* A, int lda, int K, const float* W, int ldw,
                    const float* bias, const float* resid, int ldr,
                    float* Cf, bf16* Cb, int ldc, int Mrows, int Ncols, int gelu) {
        dim3 grid(Ncols / BN, Mrows / BM);
        gemm_kernel<<<grid, b256, 0, stream>>>(A, lda, K, W, ldw, bias, resid, ldr,
                                               Cf, Cb, ldc, gelu);
    };

    embed_h_kernel<<<(M_TOK * D_MODEL) / 256, b256, 0, stream>>>(x, tok_emb, pos_emb, h);
    embed_p_kernel<<<(PREFIX * D_MODEL) / 256, b256, 0, stream>>>(x, tok_emb, pos_emb, eb);

    // ---- cross-attention block ----
    ln_kernel<<<M_TOK, b256, 0, stream>>>(h, ca_ln_g, ca_ln_b, xnb);
    gemm(xnb, D_MODEL, D_MODEL, ca_wq, INNER, nullptr, nullptr, 0,
         nullptr, qb, INNER, M_TOK, INNER, 0);
    gemm(eb, D_MODEL, D_MODEL, ca_wkv, 2 * INNER, nullptr, nullptr, 0,
         nullptr, kvb, 2 * INNER, PREFIX, 2 * INNER, 0);
    gemm(xnb, D_MODEL, D_MODEL, ca_wkv, 2 * INNER, nullptr, nullptr, 0,
         nullptr, kvb + (size_t)PREFIX * 2 * INNER, 2 * INNER, M_TOK, 2 * INNER, 0);
    attn_kernel<<<M_TOK * NH, b256, 0, stream>>>(qb, INNER, kvb, 2 * INNER,
                                                 kvb + INNER, 2 * INNER, aob, INNER, PREFIX);
    gemm(aob, INNER, INNER, ca_wo, D_MODEL, ca_bo, h, D_MODEL,
         h, nullptr, D_MODEL, M_TOK, D_MODEL, 0);

    // ---- cross ffwd ----
    ln_kernel<<<M_TOK, b256, 0, stream>>>(h, cf_ln_g, cf_ln_b, xnb);
    gemm(xnb, D_MODEL, D_MODEL, cf_w1, FF_DIM, nullptr, nullptr, 0,
         nullptr, ffb, FF_DIM, M_TOK, FF_DIM, 1);
    gemm(ffb, FF_DIM, FF_DIM, cf_w2, D_MODEL, nullptr, h, D_MODEL,
         h, nullptr, D_MODEL, M_TOK, D_MODEL, 0);

    // ---- 4 self-attention transformer blocks ----
    for (int l = 0; l < DEPTH; l++) {
        ln_kernel<<<M_TOK, b256, 0, stream>>>(h, la_ln_g + l * D_MODEL,
                                              la_ln_b + l * D_MODEL, xnb);
        gemm(xnb, D_MODEL, D_MODEL, la_wqkv + (size_t)l * D_MODEL * 3 * INNER, 3 * INNER,
             nullptr, nullptr, 0, nullptr, qkvb, 3 * INNER, M_TOK, 3 * INNER, 0);
        attn_kernel<<<M_TOK * NH, b256, 0, stream>>>(qkvb, 3 * INNER,
                                                     qkvb + INNER, 3 * INNER,
                                                     qkvb + 2 * INNER, 3 * INNER,
                                                     aob, INNER, 0);
        gemm(aob, INNER, INNER, la_wo + (size_t)l * INNER * D_MODEL, D_MODEL,
             nullptr, h, D_MODEL, h, nullptr, D_MODEL, M_TOK, D_MODEL, 0);
        ln_kernel<<<M_TOK, b256, 0, stream>>>(h, lf_ln_g + l * D_MODEL,
                                              lf_ln_b + l * D_MODEL, xnb);
        gemm(xnb, D_MODEL, D_MODEL, lf_w1 + (size_t)l * D_MODEL * FF_DIM, FF_DIM,
             nullptr, nullptr, 0, nullptr, ffb, FF_DIM, M_TOK, FF_DIM, 1);
        gemm(ffb, FF_DIM, FF_DIM, lf_w2 + (size_t)l * FF_DIM * D_MODEL, D_MODEL,
             nullptr, h, D_MODEL, h, (l == DEPTH - 1) ? hb : nullptr, D_MODEL,
             M_TOK, D_MODEL, 0);
    }

    // ---- logits head ----
    gemm(hb, D_MODEL, D_MODEL, w_logits, VOCAB, nullptr, nullptr, 0,
         out, nullptr, VOCAB, M_TOK, VOCAB, 0);
}